// Round 8
// baseline (171.660 us; speedup 1.0000x reference)
//
#include <hip/hip_runtime.h>
#include <cstdint>

#define BLOCK_SIZE 256
#define NPOS 63          // 9*7 spatial positions per batch
#define BPB  16          // batches per block = 4 waves x 4 batches/wave

typedef __attribute__((ext_vector_type(8))) _Float16 f16x8;     // 8 f16, 4 VGPRs
typedef __attribute__((ext_vector_type(4))) float f32x4;
typedef __attribute__((ext_vector_type(4))) unsigned int uint4v;

// f32 -> f16 RNE bits (low 16) — v_cvt_f16_f32 (default RNE)
__device__ __forceinline__ unsigned rne_f16(float a) {
    _Float16 h = (_Float16)a;
    return (unsigned)__builtin_bit_cast(unsigned short, h);
}
// pack two f32 -> 2 f16 RTZ in ONE v_cvt_pkrtz_f16_f32 (short0=a, short1=b)
__device__ __forceinline__ unsigned pack_f16(float a, float b) {
    auto t = __builtin_amdgcn_cvt_pkrtz(a, b);
    return __builtin_bit_cast(unsigned, t);
}

// R21 -> R22: FORCE THE REGISTER BUDGET WITH amdgpu_waves_per_eu. R21's
// launch_bounds(256,2) was a no-op (VGPR=100, WRITE=86MB unchanged):
// min-waves is only a LOWER bound on occupancy / upper bound on VGPRs —
// the allocator's heuristic still TARGETED ~5 waves/EU and spilled to
// reach it. amdgpu_waves_per_eu(1,2) caps the occupancy TARGET at 2
// waves/EU -> RA allocates up to 256 VGPRs for the ~190-reg quad-batch
// working set instead of spilling. min=1 degrades to fewer waves rather
// than spill if pressure exceeds 256.
// Tripwire: VGPR_Count must read ~180-220 and WRITE_SIZE ~16 MB. If
// VGPR still reads 100, the attribute path is dead -> revert to R19.
// Everything else byte-identical to R21 (quad-batch interleaved ILP).
__global__ __launch_bounds__(BLOCK_SIZE)
__attribute__((amdgpu_waves_per_eu(1, 2)))
void carnet_fused(
    const float* __restrict__ x,      // (B, 9, 7) flat
    const int*   __restrict__ adj,    // (B, 45)
    const float* __restrict__ ctx,    // (B, 45)
    const float* __restrict__ gcn_W,  // (7, 7)
    const float* __restrict__ gcn_b,  // (7)
    const float* __restrict__ ctx_W,  // (45, 63)
    const float* __restrict__ ctx_b,  // (63)
    const float* __restrict__ W1,     // (64, 2)
    const float* __restrict__ b1,     // (64)
    const float* __restrict__ W2,     // (64, 64)
    const float* __restrict__ b2,     // (64)
    const float* __restrict__ W3,     // (2, 64)
    const float* __restrict__ b3,     // (2)
    float* __restrict__ out,          // (B, 2, 9, 7) flat
    const int nbatch)
{
    __shared__ short sh2b[64 * 64];   // 8192 B, XOR-swizzled, RNE f16 of W2
    __shared__ float w3b2[192];       // [0..127] = W3 (2x64), [128..191] = b2

    const int t    = threadIdx.x;
    const int lane = t & 63;

    // ---- staging: W2 fp32 -> RNE f16 plane, swizzled LDS write ----
    {
        const int r  = t >> 2;
        const int cq = t & 3;
        const float* wsrc = W2 + r * 64 + cq * 16;
        const float4 w0 = ((const float4*)wsrc)[0];
        const float4 w1 = ((const float4*)wsrc)[1];
        const float4 w2v = ((const float4*)wsrc)[2];
        const float4 w3v = ((const float4*)wsrc)[3];
        uint4v hA = { rne_f16(w0.x)  | (rne_f16(w0.y)  << 16),
                      rne_f16(w0.z)  | (rne_f16(w0.w)  << 16),
                      rne_f16(w1.x)  | (rne_f16(w1.y)  << 16),
                      rne_f16(w1.z)  | (rne_f16(w1.w)  << 16) };
        uint4v hB = { rne_f16(w2v.x) | (rne_f16(w2v.y) << 16),
                      rne_f16(w2v.z) | (rne_f16(w2v.w) << 16),
                      rne_f16(w3v.x) | (rne_f16(w3v.y) << 16),
                      rne_f16(w3v.z) | (rne_f16(w3v.w) << 16) };
        const int sA = ((2 * cq)     ^ (r & 7)) * 8;
        const int sB = ((2 * cq + 1) ^ (r & 7)) * 8;
        *(uint4v*)&sh2b[r * 64 + sA] = hA;
        *(uint4v*)&sh2b[r * 64 + sB] = hB;
        if (t < 192) w3b2[t] = (t < 128) ? W3[t] : b2[t - 128];
    }

    // ---- four wave-uniform batches per wave ----
    const int bbase = blockIdx.x * BPB + (t >> 6);
    int  bs[4];
    bool vld[4];
#pragma unroll
    for (int u = 0; u < 4; ++u) {
        const int braw = bbase + u * 4;
        vld[u] = (braw < nbatch);
        bs[u]  = __builtin_amdgcn_readfirstlane(vld[u] ? braw : (nbatch - 1));
    }

    const int p = lane < 63 ? lane : 62;
    const int n = p / 7;
    const int f = p - n * 7;
    const int snn = 9 * n - (n * (n - 1)) / 2 - n;

    // ========== PHASE 1 (quad, interleaved chains) ==========
    uint64_t am[4];
#pragma unroll
    for (int u = 0; u < 4; ++u) {
        int av = 0;
        if (lane < 45) av = adj[bs[u] * 45 + lane];
        am[u] = __ballot(av != 0);
    }

    float d[4][9];
#pragma unroll
    for (int i = 0; i < 9; ++i) {
        const int s = 9 * i - (i * (i - 1)) / 2;
        const uint64_t mk = (1ull << (8 - i)) - 1ull;
#pragma unroll
        for (int u = 0; u < 4; ++u)
            d[u][i] = __frsqrt_rn((float)(1 + __popcll((am[u] >> (s + 1)) & mk)));
    }

    float yv[4] = {0.f, 0.f, 0.f, 0.f};
#pragma unroll
    for (int k = 0; k < 7; ++k) {
        const float g = gcn_W[k * 7 + f];            // shared across 4 batches
#pragma unroll
        for (int u = 0; u < 4; ++u)
            yv[u] = fmaf(x[bs[u] * 63 + n * 7 + k], g, yv[u]);
    }

    // z dot: one acc per batch (4 interleaved chains supply the ILP)
    float zt[4] = {0.f, 0.f, 0.f, 0.f};
#pragma unroll
    for (int m = 0; m < 9; ++m) {
        int sh = snn + m;
        sh = sh < 0 ? 0 : sh;
        const bool up = (m > n);
#pragma unroll
        for (int u = 0; u < 4; ++u) {
            const float ym = __shfl(yv[u], m * 7 + f);
            const float tm = ((m == n) || (up && ((am[u] >> sh) & 1ull))) ? d[u][m] : 0.f;
            zt[u] = fmaf(tm, ym, zt[u]);
        }
    }
    const float gbf = gcn_b[f];
    float zv[4];
#pragma unroll
    for (int u = 0; u < 4; ++u) zv[u] = fmaf(d[u][n], zt[u], gbf);

    // ctx dots: weight column loads shared across 4 batches; 2 accs/batch
    const float cbias = ctx_b[p];
    float c0[4] = {cbias, cbias, cbias, cbias};
    float c1[4] = {0.f, 0.f, 0.f, 0.f};
#pragma unroll
    for (int q = 0; q < 44; q += 2) {
        const float w0 = ctx_W[q * 63 + p];
        const float w1 = ctx_W[(q + 1) * 63 + p];
#pragma unroll
        for (int u = 0; u < 4; ++u) {
            c0[u] = fmaf(ctx[bs[u] * 45 + q],     w0, c0[u]);
            c1[u] = fmaf(ctx[bs[u] * 45 + q + 1], w1, c1[u]);
        }
    }
    const float w44 = ctx_W[44 * 63 + p];
    float cvv[4];
#pragma unroll
    for (int u = 0; u < 4; ++u) {
        c0[u] = fmaf(ctx[bs[u] * 45 + 44], w44, c0[u]);
        cvv[u] = fmaxf(c0[u] + c1[u], 0.f);
    }

    // ========== PHASE 2: MFMA (operand-swapped, f16, quad-batch) ==========
    const int cl   = lane & 15;       // position within i-tile (B-operand n)
    const int quad = lane >> 4;       // k-octet / C row group (channel)
    const int s0 = (quad ^ (cl & 7)) * 16;

    float2 wp0[8], wp1[8];
    float  bb0[8], bb1[8];
#pragma unroll
    for (int j = 0; j < 8; ++j) {
        const int o = quad * 8 + j;
        wp0[j] = *(const float2*)(W1 + 2 * o);
        bb0[j] = b1[o];
        wp1[j] = *(const float2*)(W1 + 2 * (o + 32));
        bb1[j] = b1[o + 32];
    }
    const float b30 = b3[0], b31 = b3[1];

    float* __restrict__ ob[4];
#pragma unroll
    for (int u = 0; u < 4; ++u) ob[u] = out + bs[u] * 126;

    const char* sh2bB_ = (const char*)sh2b;

    __syncthreads();   // staging complete before first B read

#pragma unroll 1
    for (int i = 0; i < 4; ++i) {
        float zm[4], cm[4];
#pragma unroll
        for (int u = 0; u < 4; ++u) {
            zm[u] = __shfl(zv[u],  i * 16 + cl);
            cm[u] = __shfl(cvv[u], i * 16 + cl);
        }

        // b2 quads from LDS (anti-LICM tie keeps them out of the
        // loop-invariant register set; broadcast reads, conflict-free)
        f32x4 bq_[4];
#pragma unroll
        for (int k2 = 0; k2 < 4; ++k2) {
            int o = 128 + k2 * 16 + quad * 4;
            asm volatile("" : "+v"(o));
            bq_[k2] = *(const f32x4*)&w3b2[o];
        }

        // h1 fragments for all four batches (independent chains)
        f16x8 ah0[4], ah1[4];
#pragma unroll
        for (int u = 0; u < 4; ++u) {
            uint4v p0, p1;
#pragma unroll
            for (int jj = 0; jj < 4; ++jj) {
                float ha = fmaxf(fmaf(wp0[2*jj].x,   zm[u], fmaf(wp0[2*jj].y,   cm[u], bb0[2*jj])),   0.f);
                float hb = fmaxf(fmaf(wp0[2*jj+1].x, zm[u], fmaf(wp0[2*jj+1].y, cm[u], bb0[2*jj+1])), 0.f);
                p0[jj] = pack_f16(ha, hb);
                ha = fmaxf(fmaf(wp1[2*jj].x,   zm[u], fmaf(wp1[2*jj].y,   cm[u], bb1[2*jj])),   0.f);
                hb = fmaxf(fmaf(wp1[2*jj+1].x, zm[u], fmaf(wp1[2*jj+1].y, cm[u], bb1[2*jj+1])), 0.f);
                p1[jj] = pack_f16(ha, hb);
            }
            ah0[u] = __builtin_bit_cast(f16x8, p0);
            ah1[u] = __builtin_bit_cast(f16x8, p1);
        }

        f32x4 acc[4][4];
#pragma unroll
        for (int u = 0; u < 4; ++u)
#pragma unroll
            for (int k2 = 0; k2 < 4; ++k2)
                acc[u][k2] = bq_[k2];

        // A = W2 f16 frag (LDS): 2 ds_read_b128 feed EIGHT MFMAs (4 batches)
#pragma unroll
        for (int nt = 0; nt < 4; ++nt) {
            int bo = cl * 128 + s0;
            asm volatile("" : "+v"(bo));
            const int bo2 = (cl * 128) | (s0 ^ 64);
            const f16x8 wf0 = *(const f16x8*)(sh2bB_ + bo  + nt * 2048);
            const f16x8 wf1 = *(const f16x8*)(sh2bB_ + bo2 + nt * 2048);
#pragma unroll
            for (int u = 0; u < 4; ++u) {
                acc[u][nt] = __builtin_amdgcn_mfma_f32_16x16x32_f16(wf0, ah0[u], acc[u][nt], 0, 0, 0);
                acc[u][nt] = __builtin_amdgcn_mfma_f32_16x16x32_f16(wf1, ah1[u], acc[u][nt], 0, 0, 0);
            }
        }

        // W3 rows from LDS (anti-LICM tie, broadcast reads)
        f32x4 wa_[4], wb_[4];
#pragma unroll
        for (int k2 = 0; k2 < 4; ++k2) {
            int o = k2 * 16 + quad * 4;
            asm volatile("" : "+v"(o));
            wa_[k2] = *(const f32x4*)&w3b2[o];
            wb_[k2] = *(const f32x4*)&w3b2[64 + o];
        }

        // Epilogue (channel-major): relu + W3 dot, quad-reduce, store
        const int pp = i * 16 + cl;
#pragma unroll
        for (int u = 0; u < 4; ++u) {
            float q0 = 0.f, q1 = 0.f;
#pragma unroll
            for (int k2 = 0; k2 < 4; ++k2) {
#pragma unroll
                for (int e = 0; e < 4; ++e) {
                    const float h = fmaxf(acc[u][k2][e], 0.f);
                    q0 = fmaf(h, wa_[k2][e], q0);
                    q1 = fmaf(h, wb_[k2][e], q1);
                }
            }
            q0 += __shfl_xor(q0, 16); q0 += __shfl_xor(q0, 32);
            q1 += __shfl_xor(q1, 16); q1 += __shfl_xor(q1, 32);
            if (quad == 0 && pp < NPOS && vld[u]) {
                ob[u][pp]        = q0 + b30;
                ob[u][NPOS + pp] = q1 + b31;
            }
        }
    }
}

extern "C" void kernel_launch(void* const* d_in, const int* in_sizes, int n_in,
                              void* d_out, int out_size, void* d_ws, size_t ws_size,
                              hipStream_t stream) {
    const float* x     = (const float*)d_in[0];
    const int*   adj   = (const int*)  d_in[1];
    const float* ctx   = (const float*)d_in[2];
    const float* gcn_W = (const float*)d_in[3];
    const float* gcn_b = (const float*)d_in[4];
    const float* ctx_W = (const float*)d_in[5];
    const float* ctx_b = (const float*)d_in[6];
    const float* W1    = (const float*)d_in[7];
    const float* b1    = (const float*)d_in[8];
    const float* W2    = (const float*)d_in[9];
    const float* b2    = (const float*)d_in[10];
    const float* W3    = (const float*)d_in[11];
    const float* b3    = (const float*)d_in[12];
    float* out = (float*)d_out;

    const int nbatch = in_sizes[1] / 45;            // B = 32768
    const int grid = (nbatch + BPB - 1) / BPB;      // 16 batches per block
    carnet_fused<<<grid, BLOCK_SIZE, 0, stream>>>(
        x, adj, ctx, gcn_W, gcn_b, ctx_W, ctx_b,
        W1, b1, W2, b2, W3, b3, out, nbatch);
}

// Round 9
// 154.564 us; speedup vs baseline: 1.1106x; 1.1106x over previous
//
#include <hip/hip_runtime.h>
#include <cstdint>

#define BLOCK_SIZE 256
#define NPOS 63          // 9*7 spatial positions per batch
#define NB   3           // batches per wave (triple-batch ILP)
#define BPB  12          // batches per block = 4 waves x 3 batches/wave

typedef __attribute__((ext_vector_type(8))) _Float16 f16x8;     // 8 f16, 4 VGPRs
typedef __attribute__((ext_vector_type(4))) float f32x4;
typedef __attribute__((ext_vector_type(4))) unsigned int uint4v;

// f32 -> f16 RNE bits (low 16) — v_cvt_f16_f32 (default RNE)
__device__ __forceinline__ unsigned rne_f16(float a) {
    _Float16 h = (_Float16)a;
    return (unsigned)__builtin_bit_cast(unsigned short, h);
}
// pack two f32 -> 2 f16 RTZ in ONE v_cvt_pkrtz_f16_f32 (short0=a, short1=b)
__device__ __forceinline__ unsigned pack_f16(float a, float b) {
    auto t = __builtin_amdgcn_cvt_pkrtz(a, b);
    return __builtin_bit_cast(unsigned, t);
}

// R22 -> R23: TRIPLE-BATCH, PRESSURE-SHAPED. Quad-batch (~190-reg peak)
// was refused by the RA three different ways (scratch spill x2, LDS spill
// w/ 65536 bank conflicts; VGPR_Count pinned at 100 every time). R17
// proved the allocator happily allocates 124 with zero spill, so target
// ~125: width=3 PLUS invariant-pressure cut — W1/b1 (48 regs of
// loop-invariant broadcast weights) join W3/b2 in the LDS side-buffer
// (R20-proven conflict-free: quad-uniform broadcast reads), re-read per
// i-tile (anti-LICM asm ties), shared by all 3 batches.
// Tripwire: VGPR must read 120-140 with WRITE ~16 MB / LDS ~9.7 KB.
// If VGPR=100 + spill counters again -> revert to exact R19 next round.
// Per-batch arithmetic bit-identical to R19/R20 (f16 single-product MFMA).
__global__ __launch_bounds__(BLOCK_SIZE) void carnet_fused(
    const float* __restrict__ x,      // (B, 9, 7) flat
    const int*   __restrict__ adj,    // (B, 45)
    const float* __restrict__ ctx,    // (B, 45)
    const float* __restrict__ gcn_W,  // (7, 7)
    const float* __restrict__ gcn_b,  // (7)
    const float* __restrict__ ctx_W,  // (45, 63)
    const float* __restrict__ ctx_b,  // (63)
    const float* __restrict__ W1,     // (64, 2)
    const float* __restrict__ b1,     // (64)
    const float* __restrict__ W2,     // (64, 64)
    const float* __restrict__ b2,     // (64)
    const float* __restrict__ W3,     // (2, 64)
    const float* __restrict__ b3,     // (2)
    float* __restrict__ out,          // (B, 2, 9, 7) flat
    const int nbatch)
{
    __shared__ short sh2b[64 * 64];   // 8192 B, XOR-swizzled, RNE f16 of W2
    // wbuf: [0..127]=W3(2x64), [128..191]=b2, [192..319]=W1(64x2), [320..383]=b1
    __shared__ float wbuf[384];

    const int t    = threadIdx.x;
    const int lane = t & 63;

    // ---- staging: W2 fp32 -> RNE f16 plane, swizzled LDS write ----
    {
        const int r  = t >> 2;
        const int cq = t & 3;
        const float* wsrc = W2 + r * 64 + cq * 16;
        const float4 w0 = ((const float4*)wsrc)[0];
        const float4 w1 = ((const float4*)wsrc)[1];
        const float4 w2v = ((const float4*)wsrc)[2];
        const float4 w3v = ((const float4*)wsrc)[3];
        uint4v hA = { rne_f16(w0.x)  | (rne_f16(w0.y)  << 16),
                      rne_f16(w0.z)  | (rne_f16(w0.w)  << 16),
                      rne_f16(w1.x)  | (rne_f16(w1.y)  << 16),
                      rne_f16(w1.z)  | (rne_f16(w1.w)  << 16) };
        uint4v hB = { rne_f16(w2v.x) | (rne_f16(w2v.y) << 16),
                      rne_f16(w2v.z) | (rne_f16(w2v.w) << 16),
                      rne_f16(w3v.x) | (rne_f16(w3v.y) << 16),
                      rne_f16(w3v.z) | (rne_f16(w3v.w) << 16) };
        const int sA = ((2 * cq)     ^ (r & 7)) * 8;
        const int sB = ((2 * cq + 1) ^ (r & 7)) * 8;
        *(uint4v*)&sh2b[r * 64 + sA] = hA;
        *(uint4v*)&sh2b[r * 64 + sB] = hB;
        // side-buffer: W3 | b2 | W1 | b1
        {
            float v;
            if (t < 128)      v = W3[t];
            else if (t < 192) v = b2[t - 128];
            else              v = W1[t - 192];       // t 192..255 -> W1[0..63]
            wbuf[t] = v;
            if (t < 128) {
                const int i2 = 256 + t;
                wbuf[i2] = (i2 < 320) ? W1[i2 - 192] : b1[i2 - 320];
            }
        }
    }

    // ---- three wave-uniform batches per wave ----
    const int bbase = blockIdx.x * BPB + (t >> 6);
    int  bs[NB];
    bool vld[NB];
#pragma unroll
    for (int u = 0; u < NB; ++u) {
        const int braw = bbase + u * 4;
        vld[u] = (braw < nbatch);
        bs[u]  = __builtin_amdgcn_readfirstlane(vld[u] ? braw : (nbatch - 1));
    }

    const int p = lane < 63 ? lane : 62;
    const int n = p / 7;
    const int f = p - n * 7;
    const int snn = 9 * n - (n * (n - 1)) / 2 - n;

    // ========== PHASE 1 (triple, interleaved chains) ==========
    uint64_t am[NB];
#pragma unroll
    for (int u = 0; u < NB; ++u) {
        int av = 0;
        if (lane < 45) av = adj[bs[u] * 45 + lane];
        am[u] = __ballot(av != 0);
    }

    float d[NB][9];
#pragma unroll
    for (int i = 0; i < 9; ++i) {
        const int s = 9 * i - (i * (i - 1)) / 2;
        const uint64_t mk = (1ull << (8 - i)) - 1ull;
#pragma unroll
        for (int u = 0; u < NB; ++u)
            d[u][i] = __frsqrt_rn((float)(1 + __popcll((am[u] >> (s + 1)) & mk)));
    }

    float yv[NB] = {0.f, 0.f, 0.f};
#pragma unroll
    for (int k = 0; k < 7; ++k) {
        const float g = gcn_W[k * 7 + f];            // shared across batches
#pragma unroll
        for (int u = 0; u < NB; ++u)
            yv[u] = fmaf(x[bs[u] * 63 + n * 7 + k], g, yv[u]);
    }

    // z dot: one acc per batch (3 interleaved chains supply the ILP)
    float zt[NB] = {0.f, 0.f, 0.f};
#pragma unroll
    for (int m = 0; m < 9; ++m) {
        int sh = snn + m;
        sh = sh < 0 ? 0 : sh;
        const bool up = (m > n);
#pragma unroll
        for (int u = 0; u < NB; ++u) {
            const float ym = __shfl(yv[u], m * 7 + f);
            const float tm = ((m == n) || (up && ((am[u] >> sh) & 1ull))) ? d[u][m] : 0.f;
            zt[u] = fmaf(tm, ym, zt[u]);
        }
    }
    const float gbf = gcn_b[f];
    float zv[NB];
#pragma unroll
    for (int u = 0; u < NB; ++u) zv[u] = fmaf(d[u][n], zt[u], gbf);

    // ctx dots: weight column loads shared across batches; 2 accs/batch
    const float cbias = ctx_b[p];
    float c0[NB] = {cbias, cbias, cbias};
    float c1[NB] = {0.f, 0.f, 0.f};
#pragma unroll
    for (int q = 0; q < 44; q += 2) {
        const float w0 = ctx_W[q * 63 + p];
        const float w1 = ctx_W[(q + 1) * 63 + p];
#pragma unroll
        for (int u = 0; u < NB; ++u) {
            c0[u] = fmaf(ctx[bs[u] * 45 + q],     w0, c0[u]);
            c1[u] = fmaf(ctx[bs[u] * 45 + q + 1], w1, c1[u]);
        }
    }
    const float w44 = ctx_W[44 * 63 + p];
    float cvv[NB];
#pragma unroll
    for (int u = 0; u < NB; ++u) {
        c0[u] = fmaf(ctx[bs[u] * 45 + 44], w44, c0[u]);
        cvv[u] = fmaxf(c0[u] + c1[u], 0.f);
    }

    // ========== PHASE 2: MFMA (operand-swapped, f16, triple-batch) =======
    const int cl   = lane & 15;       // position within i-tile (B-operand n)
    const int quad = lane >> 4;       // k-octet / C row group (channel)
    const int s0 = (quad ^ (cl & 7)) * 16;

    const float b30 = b3[0], b31 = b3[1];

    float* __restrict__ ob[NB];
#pragma unroll
    for (int u = 0; u < NB; ++u) ob[u] = out + bs[u] * 126;

    const char* sh2bB_ = (const char*)sh2b;

    __syncthreads();   // staging complete before first LDS read

#pragma unroll 1
    for (int i = 0; i < 4; ++i) {
        float zm[NB], cm[NB];
#pragma unroll
        for (int u = 0; u < NB; ++u) {
            zm[u] = __shfl(zv[u],  i * 16 + cl);
            cm[u] = __shfl(cvv[u], i * 16 + cl);
        }

        // h1-stage weights from LDS (anti-LICM ties: re-read per i-tile,
        // shared by all 3 batches; quad-uniform -> broadcast, conflict-free)
        // w1a[jj] = {W1[2r],W1[2r+1],W1[2r+2],W1[2r+3]} for r=quad*8+2jj
        f32x4 w1a[4], w1b[4], bbA2[2], bbB2[2];
#pragma unroll
        for (int jj = 0; jj < 4; ++jj) {
            int o = 192 + quad * 16 + jj * 4;
            asm volatile("" : "+v"(o));
            w1a[jj] = *(const f32x4*)&wbuf[o];
            int o2 = 256 + quad * 16 + jj * 4;
            asm volatile("" : "+v"(o2));
            w1b[jj] = *(const f32x4*)&wbuf[o2];
        }
#pragma unroll
        for (int h = 0; h < 2; ++h) {
            int o = 320 + quad * 8 + h * 4;
            asm volatile("" : "+v"(o));
            bbA2[h] = *(const f32x4*)&wbuf[o];
            int o2 = 352 + quad * 8 + h * 4;
            asm volatile("" : "+v"(o2));
            bbB2[h] = *(const f32x4*)&wbuf[o2];
        }

        // h1 fragments for all three batches (independent chains)
        f16x8 ah0[NB], ah1[NB];
#pragma unroll
        for (int u = 0; u < NB; ++u) {
            uint4v p0, p1;
#pragma unroll
            for (int jj = 0; jj < 4; ++jj) {
                const int be = (jj & 1) * 2;
                float ha = fmaxf(fmaf(w1a[jj][0], zm[u], fmaf(w1a[jj][1], cm[u], bbA2[jj >> 1][be])),     0.f);
                float hb = fmaxf(fmaf(w1a[jj][2], zm[u], fmaf(w1a[jj][3], cm[u], bbA2[jj >> 1][be + 1])), 0.f);
                p0[jj] = pack_f16(ha, hb);
                ha = fmaxf(fmaf(w1b[jj][0], zm[u], fmaf(w1b[jj][1], cm[u], bbB2[jj >> 1][be])),     0.f);
                hb = fmaxf(fmaf(w1b[jj][2], zm[u], fmaf(w1b[jj][3], cm[u], bbB2[jj >> 1][be + 1])), 0.f);
                p1[jj] = pack_f16(ha, hb);
            }
            ah0[u] = __builtin_bit_cast(f16x8, p0);
            ah1[u] = __builtin_bit_cast(f16x8, p1);
        }

        // b2 quads from LDS (acc init)
        f32x4 acc[NB][4];
#pragma unroll
        for (int k2 = 0; k2 < 4; ++k2) {
            int o = 128 + k2 * 16 + quad * 4;
            asm volatile("" : "+v"(o));
            const f32x4 bq = *(const f32x4*)&wbuf[o];
#pragma unroll
            for (int u = 0; u < NB; ++u) acc[u][k2] = bq;
        }

        // A = W2 f16 frag (LDS): 2 ds_read_b128 feed SIX MFMAs (3 batches)
#pragma unroll
        for (int nt = 0; nt < 4; ++nt) {
            int bo = cl * 128 + s0;
            asm volatile("" : "+v"(bo));
            const int bo2 = (cl * 128) | (s0 ^ 64);
            const f16x8 wf0 = *(const f16x8*)(sh2bB_ + bo  + nt * 2048);
            const f16x8 wf1 = *(const f16x8*)(sh2bB_ + bo2 + nt * 2048);
#pragma unroll
            for (int u = 0; u < NB; ++u) {
                acc[u][nt] = __builtin_amdgcn_mfma_f32_16x16x32_f16(wf0, ah0[u], acc[u][nt], 0, 0, 0);
                acc[u][nt] = __builtin_amdgcn_mfma_f32_16x16x32_f16(wf1, ah1[u], acc[u][nt], 0, 0, 0);
            }
        }

        // W3 rows from LDS (anti-LICM ties, broadcast reads)
        f32x4 wa_[4], wb_[4];
#pragma unroll
        for (int k2 = 0; k2 < 4; ++k2) {
            int o = k2 * 16 + quad * 4;
            asm volatile("" : "+v"(o));
            wa_[k2] = *(const f32x4*)&wbuf[o];
            wb_[k2] = *(const f32x4*)&wbuf[64 + o];
        }

        // Epilogue (channel-major): relu + W3 dot, quad-reduce, store
        const int pp = i * 16 + cl;
#pragma unroll
        for (int u = 0; u < NB; ++u) {
            float q0 = 0.f, q1 = 0.f;
#pragma unroll
            for (int k2 = 0; k2 < 4; ++k2) {
#pragma unroll
                for (int e = 0; e < 4; ++e) {
                    const float h = fmaxf(acc[u][k2][e], 0.f);
                    q0 = fmaf(h, wa_[k2][e], q0);
                    q1 = fmaf(h, wb_[k2][e], q1);
                }
            }
            q0 += __shfl_xor(q0, 16); q0 += __shfl_xor(q0, 32);
            q1 += __shfl_xor(q1, 16); q1 += __shfl_xor(q1, 32);
            if (quad == 0 && pp < NPOS && vld[u]) {
                ob[u][pp]        = q0 + b30;
                ob[u][NPOS + pp] = q1 + b31;
            }
        }
    }
}

extern "C" void kernel_launch(void* const* d_in, const int* in_sizes, int n_in,
                              void* d_out, int out_size, void* d_ws, size_t ws_size,
                              hipStream_t stream) {
    const float* x     = (const float*)d_in[0];
    const int*   adj   = (const int*)  d_in[1];
    const float* ctx   = (const float*)d_in[2];
    const float* gcn_W = (const float*)d_in[3];
    const float* gcn_b = (const float*)d_in[4];
    const float* ctx_W = (const float*)d_in[5];
    const float* ctx_b = (const float*)d_in[6];
    const float* W1    = (const float*)d_in[7];
    const float* b1    = (const float*)d_in[8];
    const float* W2    = (const float*)d_in[9];
    const float* b2    = (const float*)d_in[10];
    const float* W3    = (const float*)d_in[11];
    const float* b3    = (const float*)d_in[12];
    float* out = (float*)d_out;

    const int nbatch = in_sizes[1] / 45;            // B = 32768
    const int grid = (nbatch + BPB - 1) / BPB;      // 12 batches per block
    carnet_fused<<<grid, BLOCK_SIZE, 0, stream>>>(
        x, adj, ctx, gcn_W, gcn_b, ctx_W, ctx_b,
        W1, b1, W2, b2, W3, b3, out, nbatch);
}